// Round 2
// baseline (3743.257 us; speedup 1.0000x reference)
//
#include <hip/hip_runtime.h>

static constexpr int gT = 256;   // time steps
static constexpr int gV = 24;    // graph nodes
static constexpr float BN_INV = 0.99999500003749969f; // 1/sqrt(1+1e-5)

// ============================= prep kernels =============================
__global__ __launch_bounds__(256) void k_prep_aeff(
    const float* __restrict__ A, const float* __restrict__ e0,
    const float* __restrict__ e1, const float* __restrict__ e2,
    float* __restrict__ aeff, float* __restrict__ csum)
{
  int tid = blockIdx.x * 256 + threadIdx.x;
  if (tid < 3 * 1728) {
    int l = tid / 1728, r = tid % 1728;
    const float* e = (l == 0) ? e0 : ((l == 1) ? e1 : e2);
    aeff[tid] = A[r] * e[r];
  }
  if (tid < 3 * 72) {
    int l = tid / 72, r = tid % 72;
    int k = r / 24, w = r % 24;
    const float* e = (l == 0) ? e0 : ((l == 1) ? e1 : e2);
    float s = 0.f;
    for (int v = 0; v < 24; ++v) { int idx = (k * 24 + v) * 24 + w; s += A[idx] * e[idx]; }
    csum[tid] = s;
  }
}

// out[(k*Cin+ci)*Cout + c] = in[(k*Cout+c)*Cin + ci]
__global__ __launch_bounds__(256) void k_transpose(
    const float* __restrict__ in, float* __restrict__ out, int K, int Cin, int Cout)
{
  int idx = blockIdx.x * 256 + threadIdx.x;
  int total = K * Cin * Cout;
  if (idx >= total) return;
  int kk = idx / Cout, c = idx % Cout;
  int k = kk / Cin, ci = kk % Cin;
  out[idx] = in[(size_t)(k * Cout + c) * Cin + ci];
}

// ============================= layer 0 GCN =============================
// fused data_bn + gcn(Cin=3,Cout=256) + bn1 + relu.  One WG per (b,t).
__global__ __launch_bounds__(256) void k_gcn0(
    const float* __restrict__ x,      // [B][T][24][3]
    const float* __restrict__ aeff,   // layer0: [3][24][24]
    const float* __restrict__ csum,   // layer0: [3][24]
    const float* __restrict__ dbg, const float* __restrict__ dbb,  // [72]
    const float* __restrict__ W0,     // [768][3]
    const float* __restrict__ gb0,    // [768]
    const float* __restrict__ g1, const float* __restrict__ b1,    // [256]
    float* __restrict__ y_out,        // [Bc][T][256][24]
    int b0)
{
  __shared__ float xbn[72];      // [cin][v]
  __shared__ float XA[216];      // [(k*3+ci)][w]
  __shared__ float WL[2304];
  __shared__ float tile[256 * 25];  // padded staging
  int t = blockIdx.x, bl = blockIdx.y, tid = threadIdx.x;
  int b = b0 + bl;

  if (tid < 72) {
    int v = tid / 3, cin = tid % 3;
    float xv = x[(((size_t)b * gT + t) * gV + v) * 3 + cin];
    xbn[cin * 24 + v] = xv * (BN_INV * dbg[tid]) + dbb[tid];
  }
  for (int i = tid; i < 2304; i += 256) WL[i] = W0[i];
  __syncthreads();

  if (tid < 216) {
    int k = tid / 72, r = tid % 72, ci = r / 24, w = r % 24;
    const float* Ak = aeff + k * 576;
    float s = 0.f;
#pragma unroll
    for (int v = 0; v < 24; ++v) s += xbn[ci * 24 + v] * Ak[v * 24 + w];
    XA[tid] = s;
  }
  __syncthreads();

  int c = tid;
  float acc[24];
#pragma unroll
  for (int w = 0; w < 24; ++w) acc[w] = 0.f;
#pragma unroll
  for (int k = 0; k < 3; ++k) {
#pragma unroll
    for (int ci = 0; ci < 3; ++ci) {
      float wv = WL[(k * 256 + c) * 3 + ci];
#pragma unroll
      for (int w = 0; w < 24; ++w) acc[w] += wv * XA[(k * 3 + ci) * 24 + w];
    }
    float gv = gb0[k * 256 + c];
#pragma unroll
    for (int w = 0; w < 24; ++w) acc[w] += gv * csum[k * 24 + w];
  }
  float s1 = BN_INV * g1[c], o1 = b1[c];
#pragma unroll
  for (int w = 0; w < 24; ++w) tile[c * 25 + w] = fmaxf(acc[w] * s1 + o1, 0.f);
  __syncthreads();

  float* ob = y_out + ((size_t)bl * gT + t) * 6144;
#pragma unroll
  for (int i = 0; i < 6; ++i) {
    int f4 = i * 256 + tid;
    int f = f4 * 4;
    float4 vv;
    vv.x = tile[((f + 0) / 24) * 25 + (f + 0) % 24];
    vv.y = tile[((f + 1) / 24) * 25 + (f + 1) % 24];
    vv.z = tile[((f + 2) / 24) * 25 + (f + 2) % 24];
    vv.w = tile[((f + 3) / 24) * 25 + (f + 3) % 24];
    ((float4*)ob)[f4] = vv;
  }
}

// ============================= layers 1,2 GCN + residual =============================
// One WG per (b,t). Computes y = relu(bn1(gcn(h))) and r = bn(res_conv(h)).
template <int CIN, int COUT>
__global__ __launch_bounds__(256) void k_gcn12(
    const float* __restrict__ h_in,   // [Bc][T][CIN][24]
    const float* __restrict__ aeffL,  // [3][24][24]
    const float* __restrict__ csumL,  // [3][24]
    const float* __restrict__ Wg,     // transposed: [(k*CIN+ci)][COUT]
    const float* __restrict__ gb,     // [3*COUT]
    const float* __restrict__ g1, const float* __restrict__ b1,
    const float* __restrict__ Wr,     // transposed: [ci][COUT]
    const float* __restrict__ rb, const float* __restrict__ rg, const float* __restrict__ rbb,
    float* __restrict__ y_out,        // [Bc][T][COUT][24]
    float* __restrict__ r_out)        // [Bc][T][COUT][24]
{
  __shared__ float hL[CIN * 24];
  __shared__ float XAk[CIN * 24];
  int t = blockIdx.x, bl = blockIdx.y, tid = threadIdx.x;
  const float* hbase = h_in + ((size_t)bl * gT + t) * CIN * 24;
  for (int i = tid; i < CIN * 24 / 4; i += 256)
    ((float4*)hL)[i] = ((const float4*)hbase)[i];
  __syncthreads();

  int wt = tid & 7, ct = tid >> 3;   // wt: 8 w-groups of 3; ct: 32 c-groups
  int w0 = wt * 3;
  constexpr int NI = COUT / 32;
  float accR[NI][3];
  float accY[NI][3];
#pragma unroll
  for (int i = 0; i < NI; ++i)
#pragma unroll
    for (int j = 0; j < 3; ++j) { accR[i][j] = 0.f; accY[i][j] = 0.f; }

  // residual 1x1 conv
#pragma unroll 4
  for (int ci = 0; ci < CIN; ++ci) {
    float x0 = hL[ci * 24 + w0], x1 = hL[ci * 24 + w0 + 1], x2 = hL[ci * 24 + w0 + 2];
    const float* wrow = Wr + (size_t)ci * COUT + ct;
#pragma unroll
    for (int i = 0; i < NI; ++i) {
      float wv = wrow[32 * i];
      accR[i][0] += wv * x0; accR[i][1] += wv * x1; accR[i][2] += wv * x2;
    }
  }

  // gcn: for each k, build XA then accumulate GEMM
  for (int k = 0; k < 3; ++k) {
    __syncthreads();
    if (tid < CIN) {
      int ci = tid;
      float hr[24];
#pragma unroll
      for (int v = 0; v < 24; ++v) hr[v] = hL[ci * 24 + v];
      const float* Ak = aeffL + k * 576;
      for (int w = 0; w < 24; ++w) {
        float s = 0.f;
#pragma unroll
        for (int v = 0; v < 24; ++v) s += hr[v] * Ak[v * 24 + w];
        XAk[ci * 24 + w] = s;
      }
    }
    __syncthreads();
    const float* Wk = Wg + (size_t)k * CIN * COUT;
#pragma unroll 4
    for (int ci = 0; ci < CIN; ++ci) {
      float x0 = XAk[ci * 24 + w0], x1 = XAk[ci * 24 + w0 + 1], x2 = XAk[ci * 24 + w0 + 2];
      const float* wrow = Wk + (size_t)ci * COUT + ct;
#pragma unroll
      for (int i = 0; i < NI; ++i) {
        float wv = wrow[32 * i];
        accY[i][0] += wv * x0; accY[i][1] += wv * x1; accY[i][2] += wv * x2;
      }
    }
  }

  __syncthreads();
  float* tY = XAk;  // reuse LDS for coalesced write staging
  float* tR = hL;
#pragma unroll
  for (int i = 0; i < NI; ++i) {
    int c = ct + 32 * i;
    float bias[3] = {0.f, 0.f, 0.f};
#pragma unroll
    for (int k = 0; k < 3; ++k) {
      float gv = gb[k * COUT + c];
      bias[0] += gv * csumL[k * 24 + w0];
      bias[1] += gv * csumL[k * 24 + w0 + 1];
      bias[2] += gv * csumL[k * 24 + w0 + 2];
    }
    float s1 = BN_INV * g1[c], o1 = b1[c];
    float sr = BN_INV * rg[c], orr = rbb[c], rbv = rb[c];
#pragma unroll
    for (int j = 0; j < 3; ++j) {
      tY[c * 24 + w0 + j] = fmaxf((accY[i][j] + bias[j]) * s1 + o1, 0.f);
      tR[c * 24 + w0 + j] = (accR[i][j] + rbv) * sr + orr;
    }
  }
  __syncthreads();
  size_t ob = ((size_t)bl * gT + t) * COUT * 24;
  for (int i = tid; i < COUT * 24 / 4; i += 256) {
    ((float4*)(y_out + ob))[i] = ((float4*)tY)[i];
    ((float4*)(r_out + ob))[i] = ((float4*)tR)[i];
  }
}

// ============================= temporal conv =============================
// z[co,t,v] = sum_{ci,dt} y[ci,t+dt-2,v]*W[co,ci,dt]; + bias, bn2, +res, relu
template <int CIO, bool HASRES>
__global__ __launch_bounds__(256) void k_tcn(
    const float* __restrict__ y_in,  // [Bc][T][CIO][24]
    const float* __restrict__ Wt,    // transposed: [(ci*5+dt)][CIO]
    const float* __restrict__ tb,    // [CIO]
    const float* __restrict__ g2, const float* __restrict__ b2,
    const float* __restrict__ res,   // [Bc][T][CIO][24] or unused
    float* __restrict__ h_out)       // [Bc][T][CIO][24]
{
  constexpr int CC = 16, CO = 64, TTT = 8;
  constexpr int STRT = CC * 24 + 4;  // 388, padded against t-stride conflicts
  __shared__ float yL[12 * STRT];
  __shared__ float WL[CC * 5 * CO];
  int t0 = blockIdx.x * TTT;
  int cob = blockIdx.y * CO;
  int bl = blockIdx.z;
  int tid = threadIdx.x;
  int g = tid & 15;        // 16 tv groups
  int cg = tid >> 4;       // 16 co groups of 4
  int co0 = cob + cg * 4;
  int tt_own = g >> 1;     // 0..7
  int v0 = (g & 1) * 12;
  float acc[4][12];
#pragma unroll
  for (int i = 0; i < 4; ++i)
#pragma unroll
    for (int j = 0; j < 12; ++j) acc[i][j] = 0.f;

  const float* ybase = y_in + (size_t)bl * gT * CIO * 24;

  for (int ci0 = 0; ci0 < CIO; ci0 += CC) {
    __syncthreads();
    // stage y tile: rows tt=0..11 (t0-2 .. t0+9), CC channels, 24 v
    for (int i = tid; i < 12 * (CC * 24 / 4); i += 256) {
      int tt = i / (CC * 24 / 4), rf = i % (CC * 24 / 4);
      int tg = t0 - 2 + tt;
      float4 vv = make_float4(0.f, 0.f, 0.f, 0.f);
      if (tg >= 0 && tg < gT)
        vv = *(const float4*)(ybase + ((size_t)tg * CIO + ci0) * 24 + rf * 4);
      *(float4*)(&yL[tt * STRT + rf * 4]) = vv;
    }
    // stage W tile: [(cc*5+dt)][CO]
    for (int i = tid; i < CC * 5 * (CO / 4); i += 256) {
      int row = i / (CO / 4), cf = i % (CO / 4);
      int cc = row / 5, dt = row % 5;
      *(float4*)(&WL[row * CO + cf * 4]) =
          *(const float4*)(Wt + ((size_t)(ci0 + cc) * 5 + dt) * CIO + cob + cf * 4);
    }
    __syncthreads();
#pragma unroll
    for (int cc = 0; cc < CC; ++cc) {
#pragma unroll
      for (int dt = 0; dt < 5; ++dt) {
        float4 w4 = *(const float4*)(&WL[(cc * 5 + dt) * CO + cg * 4]);
        const float* yp = &yL[(tt_own + dt) * STRT + cc * 24 + v0];
        float4 ya = *(const float4*)(yp);
        float4 yb = *(const float4*)(yp + 4);
        float4 yc = *(const float4*)(yp + 8);
        float yv[12] = {ya.x, ya.y, ya.z, ya.w, yb.x, yb.y, yb.z, yb.w, yc.x, yc.y, yc.z, yc.w};
        float wv[4] = {w4.x, w4.y, w4.z, w4.w};
#pragma unroll
        for (int i = 0; i < 4; ++i)
#pragma unroll
          for (int j = 0; j < 12; ++j) acc[i][j] += wv[i] * yv[j];
      }
    }
  }

  int t = t0 + tt_own;
  size_t obase = ((size_t)bl * gT + t) * CIO * 24;
#pragma unroll
  for (int i = 0; i < 4; ++i) {
    int co = co0 + i;
    float sc = BN_INV * g2[co], of = b2[co], bias = tb[co];
    float z[12];
#pragma unroll
    for (int j = 0; j < 12; ++j) z[j] = (acc[i][j] + bias) * sc + of;
    if (HASRES) {
#pragma unroll
      for (int q = 0; q < 3; ++q) {
        float4 r4 = *(const float4*)(res + obase + co * 24 + v0 + 4 * q);
        z[4 * q + 0] += r4.x; z[4 * q + 1] += r4.y; z[4 * q + 2] += r4.z; z[4 * q + 3] += r4.w;
      }
    }
#pragma unroll
    for (int q = 0; q < 3; ++q) {
      float4 o4;
      o4.x = fmaxf(z[4 * q + 0], 0.f);
      o4.y = fmaxf(z[4 * q + 1], 0.f);
      o4.z = fmaxf(z[4 * q + 2], 0.f);
      o4.w = fmaxf(z[4 * q + 3], 0.f);
      *(float4*)(h_out + obase + co * 24 + v0 + 4 * q) = o4;
    }
  }
}

// ============================= final FC =============================
__global__ __launch_bounds__(256) void k_fcn(
    const float* __restrict__ h,   // [Bc][T][64][24]
    const float* __restrict__ fw,  // [6][64]
    const float* __restrict__ fb,  // [6]
    float* __restrict__ out,       // [B][T][24][6]
    int b0)
{
  __shared__ float hLf[64 * 24];
  __shared__ float fwL[384];
  int t = blockIdx.x, bl = blockIdx.y, tid = threadIdx.x;
  int b = b0 + bl;
  const float* hb = h + ((size_t)bl * gT + t) * 64 * 24;
  for (int i = tid; i < 64 * 24 / 4; i += 256) ((float4*)hLf)[i] = ((const float4*)hb)[i];
  // FIX (R1 bug): block has 256 threads; `if (tid < 384)` left fwL[256..383]
  // (fc weight rows o=4,5) as stale LDS garbage -> absmax 2.25 on channels 4,5.
  for (int i = tid; i < 384; i += 256) fwL[i] = fw[i];
  __syncthreads();
  if (tid < 144) {
    int v = tid / 6, o = tid % 6;
    float acc = fb[o];
#pragma unroll 8
    for (int c = 0; c < 64; ++c) acc += hLf[c * 24 + v] * fwL[o * 64 + c];
    out[(((size_t)b * gT + t) * gV + v) * 6 + o] = acc;
  }
}

// ============================= host =============================
extern "C" void kernel_launch(void* const* d_in, const int* in_sizes, int n_in,
                              void* d_out, int out_size, void* d_ws, size_t ws_size,
                              hipStream_t stream) {
  const float* x    = (const float*)d_in[0];
  const float* A    = (const float*)d_in[1];
  const float* dbg  = (const float*)d_in[2];
  const float* dbb  = (const float*)d_in[3];
  const float* ei0  = (const float*)d_in[4];
  const float* ei1  = (const float*)d_in[5];
  const float* ei2  = (const float*)d_in[6];
  const float* w0g  = (const float*)d_in[7];
  const float* gb0  = (const float*)d_in[8];
  const float* g10  = (const float*)d_in[9];
  const float* b10  = (const float*)d_in[10];
  const float* tw0  = (const float*)d_in[11];
  const float* tb0  = (const float*)d_in[12];
  const float* g20  = (const float*)d_in[13];
  const float* b20  = (const float*)d_in[14];
  const float* w1g  = (const float*)d_in[15];
  const float* gb1  = (const float*)d_in[16];
  const float* g11  = (const float*)d_in[17];
  const float* b11  = (const float*)d_in[18];
  const float* tw1  = (const float*)d_in[19];
  const float* tb1  = (const float*)d_in[20];
  const float* g21  = (const float*)d_in[21];
  const float* b21  = (const float*)d_in[22];
  const float* rw1  = (const float*)d_in[23];
  const float* rb1  = (const float*)d_in[24];
  const float* rg1  = (const float*)d_in[25];
  const float* rbb1 = (const float*)d_in[26];
  const float* w2g  = (const float*)d_in[27];
  const float* gb2  = (const float*)d_in[28];
  const float* g12  = (const float*)d_in[29];
  const float* b12  = (const float*)d_in[30];
  const float* tw2  = (const float*)d_in[31];
  const float* tb2  = (const float*)d_in[32];
  const float* g22  = (const float*)d_in[33];
  const float* b22  = (const float*)d_in[34];
  const float* rw2  = (const float*)d_in[35];
  const float* rb2  = (const float*)d_in[36];
  const float* rg2  = (const float*)d_in[37];
  const float* rbb2 = (const float*)d_in[38];
  const float* fw   = (const float*)d_in[39];
  const float* fb   = (const float*)d_in[40];
  float* outp = (float*)d_out;
  float* ws = (float*)d_ws;

  // ws layout (floats)
  size_t off = 0;
  auto alloc = [&](size_t n) { size_t o = off; off += n; return o; };
  size_t oAE = alloc(3 * 1728);
  size_t oCS = alloc(3 * 72);
  size_t oW1 = alloc((size_t)3 * 256 * 128);
  size_t oW2 = alloc((size_t)3 * 128 * 64);
  size_t oR1 = alloc((size_t)256 * 128);
  size_t oR2 = alloc((size_t)128 * 64);
  size_t oT0 = alloc((size_t)256 * 5 * 256);
  size_t oT1 = alloc((size_t)128 * 5 * 128);
  size_t oT2 = alloc((size_t)64 * 5 * 64);
  off = (off + 3) & ~(size_t)3;

  const size_t perB = (size_t)256 * gT * gV;  // 1,572,864 floats per batch per region
  int Bc = 32;
  while (Bc > 1 && (off + 2ull * perB * Bc) * 4ull > ws_size) Bc >>= 1;
  float* regA = ws + off;
  float* regB = regA + perB * Bc;

  // ---- prep ----
  k_prep_aeff<<<21, 256, 0, stream>>>(A, ei0, ei1, ei2, ws + oAE, ws + oCS);
  auto tgrid = [](int n) { return dim3((n + 255) / 256); };
  k_transpose<<<tgrid(3 * 256 * 128), 256, 0, stream>>>(w1g, ws + oW1, 3, 256, 128);
  k_transpose<<<tgrid(3 * 128 * 64), 256, 0, stream>>>(w2g, ws + oW2, 3, 128, 64);
  k_transpose<<<tgrid(256 * 128), 256, 0, stream>>>(rw1, ws + oR1, 1, 256, 128);
  k_transpose<<<tgrid(128 * 64), 256, 0, stream>>>(rw2, ws + oR2, 1, 128, 64);
  k_transpose<<<tgrid(256 * 5 * 256), 256, 0, stream>>>(tw0, ws + oT0, 1, 256 * 5, 256);
  k_transpose<<<tgrid(128 * 5 * 128), 256, 0, stream>>>(tw1, ws + oT1, 1, 128 * 5, 128);
  k_transpose<<<tgrid(64 * 5 * 64), 256, 0, stream>>>(tw2, ws + oT2, 1, 64 * 5, 64);

  for (int b0 = 0; b0 < 32; b0 += Bc) {
    dim3 gbt(gT, Bc);
    size_t r1off = (size_t)Bc * gT * 128 * 24;
    size_t r2off = (size_t)Bc * gT * 64 * 24;
    // layer 0
    k_gcn0<<<gbt, 256, 0, stream>>>(x, ws + oAE, ws + oCS, dbg, dbb, w0g, gb0, g10, b10, regB, b0);
    k_tcn<256, false><<<dim3(gT / 8, 4, Bc), 256, 0, stream>>>(regB, ws + oT0, tb0, g20, b20, nullptr, regA);
    // layer 1
    k_gcn12<256, 128><<<gbt, 256, 0, stream>>>(regA, ws + oAE + 1728, ws + oCS + 72, ws + oW1,
                                               gb1, g11, b11, ws + oR1, rb1, rg1, rbb1,
                                               regB, regB + r1off);
    k_tcn<128, true><<<dim3(gT / 8, 2, Bc), 256, 0, stream>>>(regB, ws + oT1, tb1, g21, b21, regB + r1off, regA);
    // layer 2
    k_gcn12<128, 64><<<gbt, 256, 0, stream>>>(regA, ws + oAE + 2 * 1728, ws + oCS + 144, ws + oW2,
                                              gb2, g12, b12, ws + oR2, rb2, rg2, rbb2,
                                              regB, regB + r2off);
    k_tcn<64, true><<<dim3(gT / 8, 1, Bc), 256, 0, stream>>>(regB, ws + oT2, tb2, g22, b22, regB + r2off, regA);
    // final FC
    k_fcn<<<gbt, 256, 0, stream>>>(regA, fw, fb, outp, b0);
  }
  (void)in_sizes; (void)n_in; (void)out_size;
}